// Round 6
// baseline (222.557 us; speedup 1.0000x reference)
//
#include <hip/hip_runtime.h>
#include <math.h>

#define BB 2
#define CC 272
#define GG 17
#define CG 16
#define HH 128
#define WW 128
#define HWX (HH*WW)
#define AFFC 102   // 6*G
#define NSLAB (BB*GG)          // 34
#define TILES_PER_SLAB 64      // (128/16)^2
#define NWG (NSLAB*TILES_PER_SLAB)  // 2176 = 8*272
#define WGPX (NWG/8)           // 272 per XCD

// ---------------- Kernel W: weight re-layouts (one-off, tiny) ----------------
__global__ __launch_bounds__(256) void wt_kernel(
    const float* __restrict__ dc_w, const float* __restrict__ tm_w,
    float* __restrict__ dc_wt, float* __restrict__ tm_wt)
{
    int i = blockIdx.x * 256 + threadIdx.x;
    if (i < GG * CG * 9 * CG) {
        int oc = i & 15, t = (i >> 4) % 9, c = (i / 144) % 16, g = i / 2304;
        dc_wt[i] = dc_w[((size_t)(g * 16 + oc) * 16 + c) * 9 + t];
    }
    if (i < GG * 6 * 9 * CG) {
        int c = i & 15, t = (i >> 4) % 9, j = (i / 144) % 6, ig = i / 864;
        tm_wt[i] = tm_w[((size_t)(ig * 6 + j) * 16 + c) * 9 + t];
    }
}

// ---------------- Kernel T: NCHW -> (B,G,HW,16) channel-last transpose ------
__global__ __launch_bounds__(256) void transpose_kernel(
    const float* __restrict__ x, float* __restrict__ xt)
{
    __shared__ float tile[CG][WW + 1];
    const int h = blockIdx.x & (HH - 1);
    const int g = (blockIdx.x >> 7) % GG;
    const int b = blockIdx.x / (GG * HH);
    const int tid = threadIdx.x;
    const float* src = x + (size_t)(b * CC + g * CG) * HWX + h * WW;
    for (int i = tid; i < CG * WW; i += 256) {
        int c = i >> 7, w = i & (WW - 1);
        tile[c][w] = src[(size_t)c * HWX + w];
    }
    __syncthreads();
    float* dst = xt + ((size_t)(b * GG + g) * HWX + h * WW) * CG;
    for (int i = tid; i < CG * WW; i += 256) {
        int w = i >> 4, c = i & 15;
        dst[i] = tile[c][w];   // i = w*16 + c : fully coalesced
    }
}

// ---------------- Kernel A: grouped 3x3 offset-transform conv ----------------
__global__ __launch_bounds__(256) void aff_conv_kernel(
    const float* __restrict__ xt, const float* __restrict__ tm_wt,
    const float* __restrict__ tm_b, float* __restrict__ aff)
{
    const int ig = blockIdx.y;
    const int b = blockIdx.z;
    const int tid = threadIdx.x;

    const int p = blockIdx.x * 256 + tid;
    const int h = p >> 7, w = p & (WW - 1);
    const float* xb = xt + (size_t)(b * GG + ig) * HWX * CG;
    const float* wb = tm_wt + (size_t)ig * (6 * 9 * CG);   // [j][t][c]

    float acc[6];
#pragma unroll
    for (int j = 0; j < 6; ++j) acc[j] = 0.f;

#pragma unroll 1
    for (int t = 0; t < 9; ++t) {
        int hy = h + t / 3 - 1;
        int wx = w + t % 3 - 1;
        float4 xv0 = {0,0,0,0}, xv1 = {0,0,0,0}, xv2 = {0,0,0,0}, xv3 = {0,0,0,0};
        if (hy >= 0 && hy < HH && wx >= 0 && wx < WW) {
            const float4* px = (const float4*)(xb + (size_t)(hy * WW + wx) * CG);
            xv0 = px[0]; xv1 = px[1]; xv2 = px[2]; xv3 = px[3];
        }
#pragma unroll
        for (int j = 0; j < 6; ++j) {
            const float4* wp = (const float4*)(wb + (j * 9 + t) * CG); // uniform
            float4 q0 = wp[0], q1 = wp[1], q2 = wp[2], q3 = wp[3];
            float a = acc[j];
            a = fmaf(xv0.x, q0.x, a); a = fmaf(xv0.y, q0.y, a);
            a = fmaf(xv0.z, q0.z, a); a = fmaf(xv0.w, q0.w, a);
            a = fmaf(xv1.x, q1.x, a); a = fmaf(xv1.y, q1.y, a);
            a = fmaf(xv1.z, q1.z, a); a = fmaf(xv1.w, q1.w, a);
            a = fmaf(xv2.x, q2.x, a); a = fmaf(xv2.y, q2.y, a);
            a = fmaf(xv2.z, q2.z, a); a = fmaf(xv2.w, q2.w, a);
            a = fmaf(xv3.x, q3.x, a); a = fmaf(xv3.y, q3.y, a);
            a = fmaf(xv3.z, q3.z, a); a = fmaf(xv3.w, q3.w, a);
            acc[j] = a;
        }
    }
#pragma unroll
    for (int j = 0; j < 6; ++j)
        aff[(size_t)(b * AFFC + ig * 6 + j) * HWX + p] = acc[j] + tm_b[ig * 6 + j];
}

// ---------------- Kernel C: deformable grouped conv + BN-stat partials -------
// 1D grid, XCD-chunked; 9 taps FULLY UNROLLED with literal tap constants so
// the (dy,dx) interleave scramble and ky/kx multiplies fold at compile time.
__global__ __launch_bounds__(256, 6) void deform_kernel(
    const float* __restrict__ xt, const float* __restrict__ dc_wt,
    const float* __restrict__ aff_buf, float* __restrict__ pre,
    float* __restrict__ stat_sum, float* __restrict__ stat_sqs)
{
    __shared__ float red[CG][4][2];

    const int bid = blockIdx.x;
    const int work = (bid & 7) * WGPX + (bid >> 3);
    const int slab = work / TILES_PER_SLAB;      // (b,g)
    const int tile = work % TILES_PER_SLAB;
    const int b = slab / GG;
    const int g = slab % GG;

    const int tid = threadIdx.y * 16 + threadIdx.x;
    const int h = (tile >> 3) * 16 + threadIdx.y;
    const int w = (tile & 7) * 16 + threadIdx.x;

    // 2x3 affine params for this pixel/group; channel = 51*i + 17*j + g
    float a00 = aff_buf[(size_t)(b * AFFC + (0 * 51 + 0 * 17 + g)) * HWX + h * WW + w];
    float a01 = aff_buf[(size_t)(b * AFFC + (0 * 51 + 1 * 17 + g)) * HWX + h * WW + w];
    float a02 = aff_buf[(size_t)(b * AFFC + (0 * 51 + 2 * 17 + g)) * HWX + h * WW + w];
    float a10 = aff_buf[(size_t)(b * AFFC + (1 * 51 + 0 * 17 + g)) * HWX + h * WW + w];
    float a11 = aff_buf[(size_t)(b * AFFC + (1 * 51 + 1 * 17 + g)) * HWX + h * WW + w];
    float a12 = aff_buf[(size_t)(b * AFFC + (1 * 51 + 2 * 17 + g)) * HWX + h * WW + w];

    const float* xb = xt + (size_t)(b * GG + g) * HWX * CG;
    const float* wg = dc_wt + (size_t)g * (CG * 9 * CG);   // [c][t][oc]

    float acc[CG];
#pragma unroll
    for (int oc = 0; oc < CG; ++oc) acc[oc] = 0.f;

    // TAP macro: all of T, I0, K0, I1, K1 are literals -> ky/kx in {-1,0,1}
    // fold to add/sub/drop; no runtime div/mod; no runtime-indexed arrays.
#define TAP(T, I0, K0, I1, K1) { \
        const float ky0 = (float)((K0) / 3 - 1), kx0 = (float)((K0) % 3 - 1); \
        const float ky1 = (float)((K1) / 3 - 1), kx1 = (float)((K1) % 3 - 1); \
        float dy = ((I0) ? a10 : a00) * ky0 + ((I0) ? a11 : a01) * kx0 + ((I0) ? a12 : a02); \
        float dx = ((I1) ? a10 : a00) * ky1 + ((I1) ? a11 : a01) * kx1 + ((I1) ? a12 : a02); \
        float py = (float)(h + (T) / 3 - 1) + dy; \
        float px = (float)(w + (T) % 3 - 1) + dx; \
        float y0f = floorf(py), x0f = floorf(px); \
        float wy = py - y0f, wx = px - x0f; \
        int y0 = (int)y0f, x0 = (int)x0f; \
        int y1 = y0 + 1, x1 = x0 + 1; \
        bool vy0 = (y0 >= 0) && (y0 < HH), vy1 = (y1 >= 0) && (y1 < HH); \
        bool vx0 = (x0 >= 0) && (x0 < WW), vx1 = (x1 >= 0) && (x1 < WW); \
        int y0c = min(max(y0, 0), HH - 1), y1c = min(max(y1, 0), HH - 1); \
        int x0c = min(max(x0, 0), WW - 1), x1c = min(max(x1, 0), WW - 1); \
        float w00 = (vy0 && vx0) ? (1.f - wy) * (1.f - wx) : 0.f; \
        float w01 = (vy0 && vx1) ? (1.f - wy) * wx : 0.f; \
        float w10 = (vy1 && vx0) ? wy * (1.f - wx) : 0.f; \
        float w11 = (vy1 && vx1) ? wy * wx : 0.f; \
        const float4* p00 = (const float4*)(xb + (size_t)(y0c * WW + x0c) * CG); \
        const float4* p01 = (const float4*)(xb + (size_t)(y0c * WW + x1c) * CG); \
        const float4* p10 = (const float4*)(xb + (size_t)(y1c * WW + x0c) * CG); \
        const float4* p11 = (const float4*)(xb + (size_t)(y1c * WW + x1c) * CG); \
        _Pragma("unroll") \
        for (int c4 = 0; c4 < 4; ++c4) { \
            float4 v00 = p00[c4], v01 = p01[c4], v10 = p10[c4], v11 = p11[c4]; \
            float se[4]; \
            se[0] = fmaf(w00, v00.x, fmaf(w01, v01.x, fmaf(w10, v10.x, w11 * v11.x))); \
            se[1] = fmaf(w00, v00.y, fmaf(w01, v01.y, fmaf(w10, v10.y, w11 * v11.y))); \
            se[2] = fmaf(w00, v00.z, fmaf(w01, v01.z, fmaf(w10, v10.z, w11 * v11.z))); \
            se[3] = fmaf(w00, v00.w, fmaf(w01, v01.w, fmaf(w10, v10.w, w11 * v11.w))); \
            _Pragma("unroll") \
            for (int e = 0; e < 4; ++e) { \
                float s = se[e]; \
                const float4* wp = (const float4*)(wg + ((c4 * 4 + e) * 9 + (T)) * CG); \
                float4 q0 = wp[0], q1 = wp[1], q2 = wp[2], q3 = wp[3]; \
                acc[0]  = fmaf(s, q0.x, acc[0]);  acc[1]  = fmaf(s, q0.y, acc[1]); \
                acc[2]  = fmaf(s, q0.z, acc[2]);  acc[3]  = fmaf(s, q0.w, acc[3]); \
                acc[4]  = fmaf(s, q1.x, acc[4]);  acc[5]  = fmaf(s, q1.y, acc[5]); \
                acc[6]  = fmaf(s, q1.z, acc[6]);  acc[7]  = fmaf(s, q1.w, acc[7]); \
                acc[8]  = fmaf(s, q2.x, acc[8]);  acc[9]  = fmaf(s, q2.y, acc[9]); \
                acc[10] = fmaf(s, q2.z, acc[10]); acc[11] = fmaf(s, q2.w, acc[11]); \
                acc[12] = fmaf(s, q3.x, acc[12]); acc[13] = fmaf(s, q3.y, acc[13]); \
                acc[14] = fmaf(s, q3.z, acc[14]); acc[15] = fmaf(s, q3.w, acc[15]); \
            } \
        } \
    }

    // flat e = i*9+k; tap t: e0=2t -> (I0,K0), e1=2t+1 -> (I1,K1)
    TAP(0, 0, 0, 0, 1)
    TAP(1, 0, 2, 0, 3)
    TAP(2, 0, 4, 0, 5)
    TAP(3, 0, 6, 0, 7)
    TAP(4, 0, 8, 1, 0)
    TAP(5, 1, 1, 1, 2)
    TAP(6, 1, 3, 1, 4)
    TAP(7, 1, 5, 1, 6)
    TAP(8, 1, 7, 1, 8)
#undef TAP

    // write pre-BN output + block-level BN partial sums
    const int lane = tid & 63, wave = tid >> 6;
#pragma unroll
    for (int oc = 0; oc < CG; ++oc) {
        pre[(size_t)(b * CC + g * CG + oc) * HWX + h * WW + w] = acc[oc];
    }
#pragma unroll 1
    for (int oc = 0; oc < CG; ++oc) {
        float s = acc[oc], q = acc[oc] * acc[oc];
#pragma unroll
        for (int off = 32; off > 0; off >>= 1) {
            s += __shfl_down(s, off);
            q += __shfl_down(q, off);
        }
        if (lane == 0) { red[oc][wave][0] = s; red[oc][wave][1] = q; }
    }
    __syncthreads();
    if (tid < CG) {
        float s = red[tid][0][0] + red[tid][1][0] + red[tid][2][0] + red[tid][3][0];
        float q = red[tid][0][1] + red[tid][1][1] + red[tid][2][1] + red[tid][3][1];
        int ch = g * CG + tid;
        atomicAdd(&stat_sum[ch], s);
        atomicAdd(&stat_sqs[ch], q);
    }
}

// ---------------- Kernel D: BN (training stats) + residual ReLU (in-place) ---
__global__ __launch_bounds__(256) void bn_res_relu_kernel(
    const float* __restrict__ x,
    const float* __restrict__ stat_sum, const float* __restrict__ stat_sqs,
    const float* __restrict__ gamma, const float* __restrict__ beta,
    float* __restrict__ out)
{
    int idx = blockIdx.x * 256 + threadIdx.x;
    int c = (idx >> 14) % CC;
    const float n = (float)(BB * HWX);
    float mean = stat_sum[c] / n;
    float var = stat_sqs[c] / n - mean * mean;
    float inv = rsqrtf(var + 1e-5f);
    float v = (out[idx] - mean) * inv * gamma[c] + beta[c] + x[idx];
    out[idx] = fmaxf(v, 0.f);
}

extern "C" void kernel_launch(void* const* d_in, const int* in_sizes, int n_in,
                              void* d_out, int out_size, void* d_ws, size_t ws_size,
                              hipStream_t stream)
{
    const float* x     = (const float*)d_in[0];
    const float* tm_w  = (const float*)d_in[1];
    const float* tm_b  = (const float*)d_in[2];
    const float* dc_w  = (const float*)d_in[3];
    const float* gamma = (const float*)d_in[4];
    const float* beta  = (const float*)d_in[5];
    float* out = (float*)d_out;

    float* ws = (float*)d_ws;
    float* stat_sum = ws;                         // 272 floats
    float* stat_sqs = ws + CC;                    // 272 floats
    float* dc_wt = ws + 1024;                     // 39168 floats
    float* tm_wt = dc_wt + 39424;                 // 14688 floats
    float* aff = tm_wt + 14848;                   // B*102*HW floats
    float* xt  = aff + (size_t)BB * AFFC * HWX;   // B*G*HW*16 floats

    hipMemsetAsync(stat_sum, 0, 2 * CC * sizeof(float), stream);

    wt_kernel<<<dim3(153), dim3(256), 0, stream>>>(dc_w, tm_w, dc_wt, tm_wt);
    transpose_kernel<<<dim3(BB * GG * HH), dim3(256), 0, stream>>>(x, xt);
    aff_conv_kernel<<<dim3(HWX / 256, GG, BB), dim3(256), 0, stream>>>(xt, tm_wt, tm_b, aff);
    deform_kernel<<<dim3(NWG), dim3(16, 16), 0, stream>>>(
        xt, dc_wt, aff, out /*pre*/, stat_sum, stat_sqs);
    bn_res_relu_kernel<<<dim3(BB * CC * HWX / 256), dim3(256), 0, stream>>>(
        x, stat_sum, stat_sqs, gamma, beta, out);
}

// Round 8
// 186.244 us; speedup vs baseline: 1.1950x; 1.1950x over previous
//
#include <hip/hip_runtime.h>
#include <math.h>

#define BB 2
#define CC 272
#define GG 17
#define CG 16
#define HH 128
#define WW 128
#define HWX (HH*WW)
#define AFFC 102   // 6*G
#define NSLAB (BB*GG)          // 34
#define TILES_PER_SLAB 64      // (128/16)^2
#define NWG (NSLAB*TILES_PER_SLAB)  // 2176 = 8*272
#define WGPX (NWG/8)           // 272 per XCD

typedef float f4nt __attribute__((ext_vector_type(4)));  // NT-builtin-compatible vec4

// ---------------- Kernel W: weight re-layouts (one-off, tiny) ----------------
__global__ __launch_bounds__(256) void wt_kernel(
    const float* __restrict__ dc_w, const float* __restrict__ tm_w,
    float* __restrict__ dc_wt, float* __restrict__ tm_wt)
{
    int i = blockIdx.x * 256 + threadIdx.x;
    if (i < GG * CG * 9 * CG) {
        int oc = i & 15, t = (i >> 4) % 9, c = (i / 144) % 16, g = i / 2304;
        dc_wt[i] = dc_w[((size_t)(g * 16 + oc) * 16 + c) * 9 + t];
    }
    if (i < GG * 6 * 9 * CG) {
        int c = i & 15, t = (i >> 4) % 9, j = (i / 144) % 6, ig = i / 864;
        tm_wt[i] = tm_w[((size_t)(ig * 6 + j) * 16 + c) * 9 + t];
    }
}

// ---------------- Kernel T: NCHW -> (B,G,HW,16) channel-last transpose ------
__global__ __launch_bounds__(256) void transpose_kernel(
    const float* __restrict__ x, float* __restrict__ xt)
{
    __shared__ float tile[CG][WW + 1];
    const int h = blockIdx.x & (HH - 1);
    const int g = (blockIdx.x >> 7) % GG;
    const int b = blockIdx.x / (GG * HH);
    const int tid = threadIdx.x;
    const float* src = x + (size_t)(b * CC + g * CG) * HWX + h * WW;
    for (int i = tid; i < CG * WW; i += 256) {
        int c = i >> 7, w = i & (WW - 1);
        tile[c][w] = src[(size_t)c * HWX + w];
    }
    __syncthreads();
    float* dst = xt + ((size_t)(b * GG + g) * HWX + h * WW) * CG;
    for (int i = tid; i < CG * WW; i += 256) {
        int w = i >> 4, c = i & 15;
        dst[i] = tile[c][w];   // i = w*16 + c : fully coalesced
    }
}

// ---------------- Kernel A: grouped 3x3 offset-transform conv ----------------
__global__ __launch_bounds__(256) void aff_conv_kernel(
    const float* __restrict__ xt, const float* __restrict__ tm_wt,
    const float* __restrict__ tm_b, float* __restrict__ aff)
{
    const int ig = blockIdx.y;
    const int b = blockIdx.z;
    const int tid = threadIdx.x;

    const int p = blockIdx.x * 256 + tid;
    const int h = p >> 7, w = p & (WW - 1);
    const float* xb = xt + (size_t)(b * GG + ig) * HWX * CG;
    const float* wb = tm_wt + (size_t)ig * (6 * 9 * CG);   // [j][t][c]

    float acc[6];
#pragma unroll
    for (int j = 0; j < 6; ++j) acc[j] = 0.f;

#pragma unroll 1
    for (int t = 0; t < 9; ++t) {
        int hy = h + t / 3 - 1;
        int wx = w + t % 3 - 1;
        float4 xv0 = {0,0,0,0}, xv1 = {0,0,0,0}, xv2 = {0,0,0,0}, xv3 = {0,0,0,0};
        if (hy >= 0 && hy < HH && wx >= 0 && wx < WW) {
            const float4* px = (const float4*)(xb + (size_t)(hy * WW + wx) * CG);
            xv0 = px[0]; xv1 = px[1]; xv2 = px[2]; xv3 = px[3];
        }
#pragma unroll
        for (int j = 0; j < 6; ++j) {
            const float4* wp = (const float4*)(wb + (j * 9 + t) * CG); // uniform
            float4 q0 = wp[0], q1 = wp[1], q2 = wp[2], q3 = wp[3];
            float a = acc[j];
            a = fmaf(xv0.x, q0.x, a); a = fmaf(xv0.y, q0.y, a);
            a = fmaf(xv0.z, q0.z, a); a = fmaf(xv0.w, q0.w, a);
            a = fmaf(xv1.x, q1.x, a); a = fmaf(xv1.y, q1.y, a);
            a = fmaf(xv1.z, q1.z, a); a = fmaf(xv1.w, q1.w, a);
            a = fmaf(xv2.x, q2.x, a); a = fmaf(xv2.y, q2.y, a);
            a = fmaf(xv2.z, q2.z, a); a = fmaf(xv2.w, q2.w, a);
            a = fmaf(xv3.x, q3.x, a); a = fmaf(xv3.y, q3.y, a);
            a = fmaf(xv3.z, q3.z, a); a = fmaf(xv3.w, q3.w, a);
            acc[j] = a;
        }
    }
#pragma unroll
    for (int j = 0; j < 6; ++j)
        aff[(size_t)(b * AFFC + ig * 6 + j) * HWX + p] = acc[j] + tm_b[ig * 6 + j];
}

// ---------------- Kernel C: deformable grouped conv + BN-stat partials -------
// 1D grid, XCD-chunked (4 blocks/CU -> ~2-slab L2 window per XCD).
// Taps fully unrolled with literal constants; ALL 16 gathers of a tap issued
// before any consumption (one latency stall per tap, not four).

// accumulate 16 oc for channel CH, sample S (weights = block-uniform scalar loads)
#define ACCE(T, CH, S) { \
    const float4* wp_ = (const float4*)(wg + ((CH) * 9 + (T)) * CG); \
    float4 q0 = wp_[0], q1 = wp_[1], q2 = wp_[2], q3 = wp_[3]; \
    acc[0]  = fmaf(S, q0.x, acc[0]);  acc[1]  = fmaf(S, q0.y, acc[1]); \
    acc[2]  = fmaf(S, q0.z, acc[2]);  acc[3]  = fmaf(S, q0.w, acc[3]); \
    acc[4]  = fmaf(S, q1.x, acc[4]);  acc[5]  = fmaf(S, q1.y, acc[5]); \
    acc[6]  = fmaf(S, q1.z, acc[6]);  acc[7]  = fmaf(S, q1.w, acc[7]); \
    acc[8]  = fmaf(S, q2.x, acc[8]);  acc[9]  = fmaf(S, q2.y, acc[9]); \
    acc[10] = fmaf(S, q2.z, acc[10]); acc[11] = fmaf(S, q2.w, acc[11]); \
    acc[12] = fmaf(S, q3.x, acc[12]); acc[13] = fmaf(S, q3.y, acc[13]); \
    acc[14] = fmaf(S, q3.z, acc[14]); acc[15] = fmaf(S, q3.w, acc[15]); }

#define C4M(T, C4, VA, VB, VC, VD) { \
    float s0 = fmaf(w00, VA.x, fmaf(w01, VB.x, fmaf(w10, VC.x, w11 * VD.x))); \
    float s1 = fmaf(w00, VA.y, fmaf(w01, VB.y, fmaf(w10, VC.y, w11 * VD.y))); \
    float s2 = fmaf(w00, VA.z, fmaf(w01, VB.z, fmaf(w10, VC.z, w11 * VD.z))); \
    float s3 = fmaf(w00, VA.w, fmaf(w01, VB.w, fmaf(w10, VC.w, w11 * VD.w))); \
    ACCE(T, (C4) * 4 + 0, s0) ACCE(T, (C4) * 4 + 1, s1) \
    ACCE(T, (C4) * 4 + 2, s2) ACCE(T, (C4) * 4 + 3, s3) }

#define TAP(T, I0, K0, I1, K1) { \
    float dy = ((I0) ? a10 : a00) * (float)((K0) / 3 - 1) \
             + ((I0) ? a11 : a01) * (float)((K0) % 3 - 1) + ((I0) ? a12 : a02); \
    float dx = ((I1) ? a10 : a00) * (float)((K1) / 3 - 1) \
             + ((I1) ? a11 : a01) * (float)((K1) % 3 - 1) + ((I1) ? a12 : a02); \
    float py = (float)(h + (T) / 3 - 1) + dy; \
    float px = (float)(w + (T) % 3 - 1) + dx; \
    float y0f = floorf(py), x0f = floorf(px); \
    float wy = py - y0f, wx = px - x0f; \
    int y0 = (int)y0f, x0 = (int)x0f; \
    int y1 = y0 + 1, x1 = x0 + 1; \
    bool vy0 = (y0 >= 0) && (y0 < HH), vy1 = (y1 >= 0) && (y1 < HH); \
    bool vx0 = (x0 >= 0) && (x0 < WW), vx1 = (x1 >= 0) && (x1 < WW); \
    int y0c = min(max(y0, 0), HH - 1), y1c = min(max(y1, 0), HH - 1); \
    int x0c = min(max(x0, 0), WW - 1), x1c = min(max(x1, 0), WW - 1); \
    float w00 = (vy0 && vx0) ? (1.f - wy) * (1.f - wx) : 0.f; \
    float w01 = (vy0 && vx1) ? (1.f - wy) * wx : 0.f; \
    float w10 = (vy1 && vx0) ? wy * (1.f - wx) : 0.f; \
    float w11 = (vy1 && vx1) ? wy * wx : 0.f; \
    const float4* p00 = (const float4*)(xb + (size_t)(y0c * WW + x0c) * CG); \
    const float4* p01 = (const float4*)(xb + (size_t)(y0c * WW + x1c) * CG); \
    const float4* p10 = (const float4*)(xb + (size_t)(y1c * WW + x0c) * CG); \
    const float4* p11 = (const float4*)(xb + (size_t)(y1c * WW + x1c) * CG); \
    float4 vA0 = p00[0], vA1 = p00[1], vA2 = p00[2], vA3 = p00[3]; \
    float4 vB0 = p01[0], vB1 = p01[1], vB2 = p01[2], vB3 = p01[3]; \
    float4 vC0 = p10[0], vC1 = p10[1], vC2 = p10[2], vC3 = p10[3]; \
    float4 vD0 = p11[0], vD1 = p11[1], vD2 = p11[2], vD3 = p11[3]; \
    C4M(T, 0, vA0, vB0, vC0, vD0) \
    C4M(T, 1, vA1, vB1, vC1, vD1) \
    C4M(T, 2, vA2, vB2, vC2, vD2) \
    C4M(T, 3, vA3, vB3, vC3, vD3) }

__global__ __launch_bounds__(256, 4) void deform_kernel(
    const float* __restrict__ xt, const float* __restrict__ dc_wt,
    const float* __restrict__ aff_buf, float* __restrict__ pre,
    float* __restrict__ stat_sum, float* __restrict__ stat_sqs)
{
    __shared__ float red[CG][4][2];

    const int bid = blockIdx.x;
    const int work = (bid & 7) * WGPX + (bid >> 3);
    const int slab = work / TILES_PER_SLAB;      // (b,g)
    const int tile = work % TILES_PER_SLAB;
    const int b = slab / GG;
    const int g = slab % GG;

    const int tid = threadIdx.y * 16 + threadIdx.x;
    const int h = (tile >> 3) * 16 + threadIdx.y;
    const int w = (tile & 7) * 16 + threadIdx.x;

    // 2x3 affine params (single-touch -> non-temporal); channel = 51*i+17*j+g
    const float* ab = aff_buf + (size_t)b * AFFC * HWX + h * WW + w;
    float a00 = __builtin_nontemporal_load(ab + (size_t)(0 * 51 + 0 * 17 + g) * HWX);
    float a01 = __builtin_nontemporal_load(ab + (size_t)(0 * 51 + 1 * 17 + g) * HWX);
    float a02 = __builtin_nontemporal_load(ab + (size_t)(0 * 51 + 2 * 17 + g) * HWX);
    float a10 = __builtin_nontemporal_load(ab + (size_t)(1 * 51 + 0 * 17 + g) * HWX);
    float a11 = __builtin_nontemporal_load(ab + (size_t)(1 * 51 + 1 * 17 + g) * HWX);
    float a12 = __builtin_nontemporal_load(ab + (size_t)(1 * 51 + 2 * 17 + g) * HWX);

    const float* xb = xt + (size_t)(b * GG + g) * HWX * CG;
    const float* wg = dc_wt + (size_t)g * (CG * 9 * CG);   // [c][t][oc]

    float acc[CG];
#pragma unroll
    for (int oc = 0; oc < CG; ++oc) acc[oc] = 0.f;

    // flat e = i*9+k; tap t: e0=2t -> (I0,K0), e1=2t+1 -> (I1,K1)
    TAP(0, 0, 0, 0, 1)
    TAP(1, 0, 2, 0, 3)
    TAP(2, 0, 4, 0, 5)
    TAP(3, 0, 6, 0, 7)
    TAP(4, 0, 8, 1, 0)
    TAP(5, 1, 1, 1, 2)
    TAP(6, 1, 3, 1, 4)
    TAP(7, 1, 5, 1, 6)
    TAP(8, 1, 7, 1, 8)

    // write pre-BN output (streaming, keep out of L2) + BN partial sums
    const int lane = tid & 63, wave = tid >> 6;
#pragma unroll
    for (int oc = 0; oc < CG; ++oc) {
        __builtin_nontemporal_store(acc[oc],
            &pre[(size_t)(b * CC + g * CG + oc) * HWX + h * WW + w]);
    }
#pragma unroll
    for (int oc = 0; oc < CG; ++oc) {
        float s = acc[oc], q = acc[oc] * acc[oc];
#pragma unroll
        for (int off = 32; off > 0; off >>= 1) {
            s += __shfl_down(s, off);
            q += __shfl_down(q, off);
        }
        if (lane == 0) { red[oc][wave][0] = s; red[oc][wave][1] = q; }
    }
    __syncthreads();
    if (tid < CG) {
        float s = red[tid][0][0] + red[tid][1][0] + red[tid][2][0] + red[tid][3][0];
        float q = red[tid][0][1] + red[tid][1][1] + red[tid][2][1] + red[tid][3][1];
        int ch = g * CG + tid;
        atomicAdd(&stat_sum[ch], s);
        atomicAdd(&stat_sqs[ch], q);
    }
}

// ---------------- Kernel D: BN (training stats) + residual ReLU (in-place) ---
// float4-vectorized, non-temporal streaming (ext_vector_type for NT builtins)
__global__ __launch_bounds__(256) void bn_res_relu_kernel(
    const float* __restrict__ x,
    const float* __restrict__ stat_sum, const float* __restrict__ stat_sqs,
    const float* __restrict__ gamma, const float* __restrict__ beta,
    float* __restrict__ out)
{
    int i4 = blockIdx.x * 256 + threadIdx.x;
    int idx = i4 * 4;
    int c = (idx >> 14) % CC;        // HWX=16384 divisible by 4 -> c uniform in float4
    const float n = (float)(BB * HWX);
    float mean = stat_sum[c] / n;
    float var = stat_sqs[c] / n - mean * mean;
    float inv = rsqrtf(var + 1e-5f) * gamma[c];
    float bb = beta[c];
    f4nt pv = __builtin_nontemporal_load((const f4nt*)&out[idx]);
    f4nt xv = __builtin_nontemporal_load((const f4nt*)&x[idx]);
    f4nt r;
    r.x = fmaxf(fmaf(pv.x - mean, inv, bb) + xv.x, 0.f);
    r.y = fmaxf(fmaf(pv.y - mean, inv, bb) + xv.y, 0.f);
    r.z = fmaxf(fmaf(pv.z - mean, inv, bb) + xv.z, 0.f);
    r.w = fmaxf(fmaf(pv.w - mean, inv, bb) + xv.w, 0.f);
    __builtin_nontemporal_store(r, (f4nt*)&out[idx]);
}

extern "C" void kernel_launch(void* const* d_in, const int* in_sizes, int n_in,
                              void* d_out, int out_size, void* d_ws, size_t ws_size,
                              hipStream_t stream)
{
    const float* x     = (const float*)d_in[0];
    const float* tm_w  = (const float*)d_in[1];
    const float* tm_b  = (const float*)d_in[2];
    const float* dc_w  = (const float*)d_in[3];
    const float* gamma = (const float*)d_in[4];
    const float* beta  = (const float*)d_in[5];
    float* out = (float*)d_out;

    float* ws = (float*)d_ws;
    float* stat_sum = ws;                         // 272 floats
    float* stat_sqs = ws + CC;                    // 272 floats
    float* dc_wt = ws + 1024;                     // 39168 floats
    float* tm_wt = dc_wt + 39424;                 // 14688 floats
    float* aff = tm_wt + 14848;                   // B*102*HW floats
    float* xt  = aff + (size_t)BB * AFFC * HWX;   // B*G*HW*16 floats

    (void)hipMemsetAsync(stat_sum, 0, 2 * CC * sizeof(float), stream);

    wt_kernel<<<dim3(153), dim3(256), 0, stream>>>(dc_w, tm_w, dc_wt, tm_wt);
    transpose_kernel<<<dim3(BB * GG * HH), dim3(256), 0, stream>>>(x, xt);
    aff_conv_kernel<<<dim3(HWX / 256, GG, BB), dim3(256), 0, stream>>>(xt, tm_wt, tm_b, aff);
    deform_kernel<<<dim3(NWG), dim3(16, 16), 0, stream>>>(
        xt, dc_wt, aff, out /*pre*/, stat_sum, stat_sqs);
    bn_res_relu_kernel<<<dim3(BB * CC * HWX / 4 / 256), dim3(256), 0, stream>>>(
        x, stat_sum, stat_sqs, gamma, beta, out);
}

// Round 9
// 133.631 us; speedup vs baseline: 1.6655x; 1.3937x over previous
//
#include <hip/hip_runtime.h>
#include <math.h>

#define BB 2
#define CC 272
#define GG 17
#define CG 16
#define HH 128
#define WW 128
#define HWX (HH*WW)
#define AFFC 102   // 6*G
#define NSLAB (BB*GG)          // 34
#define TILES_PER_SLAB 64      // (128/16)^2
#define NWG (NSLAB*TILES_PER_SLAB)  // 2176 = 8*272
#define WGPX (NWG/8)           // 272 per XCD

typedef float f4nt __attribute__((ext_vector_type(4)));     // NT-compatible vec4
typedef unsigned u4nt __attribute__((ext_vector_type(4)));  // NT-compatible uvec4

// bf16 helpers (RTNE pack, cheap unpack)
__device__ __forceinline__ unsigned f2bf(float f) {
    unsigned u = __float_as_uint(f);
    return (u + 0x7fffu + ((u >> 16) & 1u)) >> 16;
}
__device__ __forceinline__ float bflo(unsigned u) { return __uint_as_float(u << 16); }
__device__ __forceinline__ float bfhi(unsigned u) { return __uint_as_float(u & 0xffff0000u); }

// ---------------- Kernel W: weight re-layouts (one-off, tiny) ----------------
__global__ __launch_bounds__(256) void wt_kernel(
    const float* __restrict__ dc_w, const float* __restrict__ tm_w,
    float* __restrict__ dc_wt, float* __restrict__ tm_wt)
{
    int i = blockIdx.x * 256 + threadIdx.x;
    if (i < GG * CG * 9 * CG) {
        int oc = i & 15, t = (i >> 4) % 9, c = (i / 144) % 16, g = i / 2304;
        dc_wt[i] = dc_w[((size_t)(g * 16 + oc) * 16 + c) * 9 + t];
    }
    if (i < GG * 6 * 9 * CG) {
        int c = i & 15, t = (i >> 4) % 9, j = (i / 144) % 6, ig = i / 864;
        tm_wt[i] = tm_w[((size_t)(ig * 6 + j) * 16 + c) * 9 + t];
    }
}

// ---------------- Kernel T: NCHW -> (B,G,HW,16) channel-last bf16 ----------
__global__ __launch_bounds__(256) void transpose_kernel(
    const float* __restrict__ x, unsigned* __restrict__ xt)
{
    __shared__ float tile[CG][WW + 1];
    const int h = blockIdx.x & (HH - 1);
    const int g = (blockIdx.x >> 7) % GG;
    const int b = blockIdx.x / (GG * HH);
    const int tid = threadIdx.x;
    const float* src = x + (size_t)(b * CC + g * CG) * HWX + h * WW;
    for (int i = tid; i < CG * WW; i += 256) {
        int c = i >> 7, w = i & (WW - 1);
        tile[c][w] = src[(size_t)c * HWX + w];
    }
    __syncthreads();
    unsigned* dst = xt + ((size_t)(b * GG + g) * HWX + h * WW) * (CG / 2);
    for (int i = tid; i < CG * WW / 2; i += 256) {
        int w = i >> 3, c2 = i & 7;   // u32 i = w*8 + c2 holds channels 2c2, 2c2+1
        dst[i] = f2bf(tile[2 * c2][w]) | (f2bf(tile[2 * c2 + 1][w]) << 16);
    }
}

// ---------------- Kernel A: grouped 3x3 offset-transform conv ----------------
__global__ __launch_bounds__(256) void aff_conv_kernel(
    const unsigned* __restrict__ xt, const float* __restrict__ tm_wt,
    const float* __restrict__ tm_b, float* __restrict__ aff)
{
    const int ig = blockIdx.y;
    const int b = blockIdx.z;
    const int tid = threadIdx.x;

    const int p = blockIdx.x * 256 + tid;
    const int h = p >> 7, w = p & (WW - 1);
    const unsigned* xb = xt + (size_t)(b * GG + ig) * HWX * (CG / 2);
    const float* wb = tm_wt + (size_t)ig * (6 * 9 * CG);   // [j][t][c]

    float acc[6];
#pragma unroll
    for (int j = 0; j < 6; ++j) acc[j] = 0.f;

#pragma unroll 1
    for (int t = 0; t < 9; ++t) {
        int hy = h + t / 3 - 1;
        int wx = w + t % 3 - 1;
        uint4 u0 = {0, 0, 0, 0}, u1 = {0, 0, 0, 0};
        if (hy >= 0 && hy < HH && wx >= 0 && wx < WW) {
            const uint4* px = (const uint4*)(xb + (size_t)(hy * WW + wx) * (CG / 2));
            u0 = px[0]; u1 = px[1];
        }
        float xv[16];
        xv[0] = bflo(u0.x);  xv[1] = bfhi(u0.x);  xv[2] = bflo(u0.y);  xv[3] = bfhi(u0.y);
        xv[4] = bflo(u0.z);  xv[5] = bfhi(u0.z);  xv[6] = bflo(u0.w);  xv[7] = bfhi(u0.w);
        xv[8] = bflo(u1.x);  xv[9] = bfhi(u1.x);  xv[10] = bflo(u1.y); xv[11] = bfhi(u1.y);
        xv[12] = bflo(u1.z); xv[13] = bfhi(u1.z); xv[14] = bflo(u1.w); xv[15] = bfhi(u1.w);
#pragma unroll
        for (int j = 0; j < 6; ++j) {
            const float* wp = wb + (j * 9 + t) * CG;   // block-uniform -> s_load
            float a = acc[j];
#pragma unroll
            for (int k = 0; k < 16; ++k) a = fmaf(xv[k], wp[k], a);
            acc[j] = a;
        }
    }
#pragma unroll
    for (int j = 0; j < 6; ++j)
        aff[(size_t)(b * AFFC + ig * 6 + j) * HWX + p] = acc[j] + tm_b[ig * 6 + j];
}

// ---------------- Kernel C: deformable grouped conv + BN-stat partials -------
// 1D grid, XCD-chunked; bf16 xt gathers (8B/corner-half), bf16 channel-last pre.

#define ACCE(T, CH, S) { \
    const float4* wp_ = (const float4*)(wg + ((CH) * 9 + (T)) * CG); \
    float4 q0 = wp_[0], q1 = wp_[1], q2 = wp_[2], q3 = wp_[3]; \
    acc[0]  = fmaf(S, q0.x, acc[0]);  acc[1]  = fmaf(S, q0.y, acc[1]); \
    acc[2]  = fmaf(S, q0.z, acc[2]);  acc[3]  = fmaf(S, q0.w, acc[3]); \
    acc[4]  = fmaf(S, q1.x, acc[4]);  acc[5]  = fmaf(S, q1.y, acc[5]); \
    acc[6]  = fmaf(S, q1.z, acc[6]);  acc[7]  = fmaf(S, q1.w, acc[7]); \
    acc[8]  = fmaf(S, q2.x, acc[8]);  acc[9]  = fmaf(S, q2.y, acc[9]); \
    acc[10] = fmaf(S, q2.z, acc[10]); acc[11] = fmaf(S, q2.w, acc[11]); \
    acc[12] = fmaf(S, q3.x, acc[12]); acc[13] = fmaf(S, q3.y, acc[13]); \
    acc[14] = fmaf(S, q3.z, acc[14]); acc[15] = fmaf(S, q3.w, acc[15]); }

// one u32 pair of channels (CH, CH+1) across 4 corners
#define SE2(UA, UB, UC, UD, CH, T) { \
    float sl = fmaf(w00, bflo(UA), fmaf(w01, bflo(UB), fmaf(w10, bflo(UC), w11 * bflo(UD)))); \
    float sh = fmaf(w00, bfhi(UA), fmaf(w01, bfhi(UB), fmaf(w10, bfhi(UC), w11 * bfhi(UD)))); \
    ACCE(T, (CH), sl) ACCE(T, (CH) + 1, sh) }

#define TAP(T, I0, K0, I1, K1) { \
    float dy = ((I0) ? a10 : a00) * (float)((K0) / 3 - 1) \
             + ((I0) ? a11 : a01) * (float)((K0) % 3 - 1) + ((I0) ? a12 : a02); \
    float dx = ((I1) ? a10 : a00) * (float)((K1) / 3 - 1) \
             + ((I1) ? a11 : a01) * (float)((K1) % 3 - 1) + ((I1) ? a12 : a02); \
    float py = (float)(h + (T) / 3 - 1) + dy; \
    float px = (float)(w + (T) % 3 - 1) + dx; \
    float y0f = floorf(py), x0f = floorf(px); \
    float wy = py - y0f, wx = px - x0f; \
    int y0 = (int)y0f, x0 = (int)x0f; \
    int y1 = y0 + 1, x1 = x0 + 1; \
    bool vy0 = (y0 >= 0) && (y0 < HH), vy1 = (y1 >= 0) && (y1 < HH); \
    bool vx0 = (x0 >= 0) && (x0 < WW), vx1 = (x1 >= 0) && (x1 < WW); \
    int y0c = min(max(y0, 0), HH - 1), y1c = min(max(y1, 0), HH - 1); \
    int x0c = min(max(x0, 0), WW - 1), x1c = min(max(x1, 0), WW - 1); \
    float w00 = (vy0 && vx0) ? (1.f - wy) * (1.f - wx) : 0.f; \
    float w01 = (vy0 && vx1) ? (1.f - wy) * wx : 0.f; \
    float w10 = (vy1 && vx0) ? wy * (1.f - wx) : 0.f; \
    float w11 = (vy1 && vx1) ? wy * wx : 0.f; \
    const uint4* pA = (const uint4*)(xb + (size_t)(y0c * WW + x0c) * (CG / 2)); \
    const uint4* pB = (const uint4*)(xb + (size_t)(y0c * WW + x1c) * (CG / 2)); \
    const uint4* pC = (const uint4*)(xb + (size_t)(y1c * WW + x0c) * (CG / 2)); \
    const uint4* pD = (const uint4*)(xb + (size_t)(y1c * WW + x1c) * (CG / 2)); \
    uint4 A0 = pA[0], A1 = pA[1], B0 = pB[0], B1 = pB[1]; \
    uint4 C0 = pC[0], C1 = pC[1], D0 = pD[0], D1 = pD[1]; \
    SE2(A0.x, B0.x, C0.x, D0.x, 0, T)  SE2(A0.y, B0.y, C0.y, D0.y, 2, T) \
    SE2(A0.z, B0.z, C0.z, D0.z, 4, T)  SE2(A0.w, B0.w, C0.w, D0.w, 6, T) \
    SE2(A1.x, B1.x, C1.x, D1.x, 8, T)  SE2(A1.y, B1.y, C1.y, D1.y, 10, T) \
    SE2(A1.z, B1.z, C1.z, D1.z, 12, T) SE2(A1.w, B1.w, C1.w, D1.w, 14, T) }

__global__ __launch_bounds__(256, 6) void deform_kernel(
    const unsigned* __restrict__ xt, const float* __restrict__ dc_wt,
    const float* __restrict__ aff_buf, unsigned* __restrict__ pre,
    float* __restrict__ stat_sum, float* __restrict__ stat_sqs)
{
    __shared__ float red[CG][4][2];

    const int bid = blockIdx.x;
    const int work = (bid & 7) * WGPX + (bid >> 3);
    const int slab = work / TILES_PER_SLAB;      // (b,g)
    const int tile = work % TILES_PER_SLAB;
    const int b = slab / GG;
    const int g = slab % GG;

    const int tid = threadIdx.y * 16 + threadIdx.x;
    const int h = (tile >> 3) * 16 + threadIdx.y;
    const int w = (tile & 7) * 16 + threadIdx.x;

    // 2x3 affine params (single-touch -> non-temporal); channel = 51*i+17*j+g
    const float* ab = aff_buf + (size_t)b * AFFC * HWX + h * WW + w;
    float a00 = __builtin_nontemporal_load(ab + (size_t)(0 * 51 + 0 * 17 + g) * HWX);
    float a01 = __builtin_nontemporal_load(ab + (size_t)(0 * 51 + 1 * 17 + g) * HWX);
    float a02 = __builtin_nontemporal_load(ab + (size_t)(0 * 51 + 2 * 17 + g) * HWX);
    float a10 = __builtin_nontemporal_load(ab + (size_t)(1 * 51 + 0 * 17 + g) * HWX);
    float a11 = __builtin_nontemporal_load(ab + (size_t)(1 * 51 + 1 * 17 + g) * HWX);
    float a12 = __builtin_nontemporal_load(ab + (size_t)(1 * 51 + 2 * 17 + g) * HWX);

    const unsigned* xb = xt + (size_t)(b * GG + g) * HWX * (CG / 2);
    const float* wg = dc_wt + (size_t)g * (CG * 9 * CG);   // [c][t][oc]

    float acc[CG];
#pragma unroll
    for (int oc = 0; oc < CG; ++oc) acc[oc] = 0.f;

    // flat e = i*9+k; tap t: e0=2t -> (I0,K0), e1=2t+1 -> (I1,K1)
    TAP(0, 0, 0, 0, 1)
    TAP(1, 0, 2, 0, 3)
    TAP(2, 0, 4, 0, 5)
    TAP(3, 0, 6, 0, 7)
    TAP(4, 0, 8, 1, 0)
    TAP(5, 1, 1, 1, 2)
    TAP(6, 1, 3, 1, 4)
    TAP(7, 1, 5, 1, 6)
    TAP(8, 1, 7, 1, 8)

    // pre as bf16 channel-last [slab][px][16]: lane writes 32B contiguous (NT)
    unsigned pk[8];
#pragma unroll
    for (int k = 0; k < 8; ++k)
        pk[k] = f2bf(acc[2 * k]) | (f2bf(acc[2 * k + 1]) << 16);
    {
        u4nt q0 = {pk[0], pk[1], pk[2], pk[3]};
        u4nt q1 = {pk[4], pk[5], pk[6], pk[7]};
        u4nt* pp = (u4nt*)(pre + ((size_t)slab * HWX + h * WW + w) * (CG / 2));
        __builtin_nontemporal_store(q0, pp);
        __builtin_nontemporal_store(q1, pp + 1);
    }

    // BN partial sums from exact f32 acc
    const int lane = tid & 63, wave = tid >> 6;
#pragma unroll
    for (int oc = 0; oc < CG; ++oc) {
        float s = acc[oc], q = acc[oc] * acc[oc];
#pragma unroll
        for (int off = 32; off > 0; off >>= 1) {
            s += __shfl_down(s, off);
            q += __shfl_down(q, off);
        }
        if (lane == 0) { red[oc][wave][0] = s; red[oc][wave][1] = q; }
    }
    __syncthreads();
    if (tid < CG) {
        float s = red[tid][0][0] + red[tid][1][0] + red[tid][2][0] + red[tid][3][0];
        float q = red[tid][0][1] + red[tid][1][1] + red[tid][2][1] + red[tid][3][1];
        int ch = g * CG + tid;
        atomicAdd(&stat_sum[ch], s);
        atomicAdd(&stat_sqs[ch], q);
    }
}

// ---------------- Kernel S: per-channel scale/shift from stats ---------------
__global__ __launch_bounds__(64) void stat_finalize_kernel(
    const float* __restrict__ ssum, const float* __restrict__ ssqs,
    const float* __restrict__ gamma, const float* __restrict__ beta,
    float* __restrict__ scale, float* __restrict__ shift)
{
    int c = blockIdx.x * 64 + threadIdx.x;
    if (c >= CC) return;
    const float n = (float)(BB * HWX);
    float mean = ssum[c] / n;
    float var = ssqs[c] / n - mean * mean;
    float sc = rsqrtf(var + 1e-5f) * gamma[c];
    scale[c] = sc;
    shift[c] = fmaf(-mean, sc, beta[c]);
}

// ---------------- Kernel D: BN + residual ReLU (pre: bf16 channel-last) ------
// block = (slab, 1024-px chunk); thread: 4 px x 16 oc
__global__ __launch_bounds__(256) void bn_res_relu_kernel(
    const unsigned* __restrict__ pre, const float* __restrict__ x,
    const float* __restrict__ scale, const float* __restrict__ shift,
    float* __restrict__ out)
{
    const int blk = blockIdx.x;
    const int slab = blk >> 4;       // 16 chunks per slab
    const int chunk = blk & 15;
    const int b = slab / GG, g = slab % GG;
    const int px0 = chunk * 1024 + threadIdx.x * 4;

    // uniform per block -> scalar loads
    float sc[16], sh[16];
#pragma unroll
    for (int oc = 0; oc < 16; ++oc) {
        sc[oc] = scale[g * CG + oc];
        sh[oc] = shift[g * CG + oc];
    }

    const uint4* pp = (const uint4*)(pre + ((size_t)slab * HWX + px0) * (CG / 2));
    unsigned Pu[32];
#pragma unroll
    for (int k = 0; k < 8; ++k) {
        uint4 v = pp[k];
        Pu[4 * k] = v.x; Pu[4 * k + 1] = v.y; Pu[4 * k + 2] = v.z; Pu[4 * k + 3] = v.w;
    }
    const float* xb = x + (size_t)(b * CC + g * CG) * HWX + px0;
    float* ob = out + (size_t)(b * CC + g * CG) * HWX + px0;

#pragma unroll
    for (int oc = 0; oc < 16; ++oc) {
        f4nt xv = __builtin_nontemporal_load((const f4nt*)(xb + (size_t)oc * HWX));
        f4nt r;
        float p0, p1, p2, p3;
        {   // px i: Pu[i*8 + oc/2], lo/hi by oc&1  (oc literal after unroll)
            unsigned u0 = Pu[0 * 8 + (oc >> 1)], u1 = Pu[1 * 8 + (oc >> 1)];
            unsigned u2 = Pu[2 * 8 + (oc >> 1)], u3 = Pu[3 * 8 + (oc >> 1)];
            p0 = (oc & 1) ? bfhi(u0) : bflo(u0);
            p1 = (oc & 1) ? bfhi(u1) : bflo(u1);
            p2 = (oc & 1) ? bfhi(u2) : bflo(u2);
            p3 = (oc & 1) ? bfhi(u3) : bflo(u3);
        }
        r.x = fmaxf(fmaf(p0, sc[oc], sh[oc]) + xv.x, 0.f);
        r.y = fmaxf(fmaf(p1, sc[oc], sh[oc]) + xv.y, 0.f);
        r.z = fmaxf(fmaf(p2, sc[oc], sh[oc]) + xv.z, 0.f);
        r.w = fmaxf(fmaf(p3, sc[oc], sh[oc]) + xv.w, 0.f);
        __builtin_nontemporal_store(r, (f4nt*)(ob + (size_t)oc * HWX));
    }
}

extern "C" void kernel_launch(void* const* d_in, const int* in_sizes, int n_in,
                              void* d_out, int out_size, void* d_ws, size_t ws_size,
                              hipStream_t stream)
{
    const float* x     = (const float*)d_in[0];
    const float* tm_w  = (const float*)d_in[1];
    const float* tm_b  = (const float*)d_in[2];
    const float* dc_w  = (const float*)d_in[3];
    const float* gamma = (const float*)d_in[4];
    const float* beta  = (const float*)d_in[5];
    float* out = (float*)d_out;

    float* ws = (float*)d_ws;
    float* stat_sum = ws;                          // 272
    float* stat_sqs = ws + CC;                     // 272
    float* scale    = ws + 2 * CC;                 // 272
    float* shift    = ws + 3 * CC;                 // 272
    float* dc_wt = ws + 2048;                      // 39168 floats
    float* tm_wt = dc_wt + 39424;                  // 14688 floats
    float* aff   = tm_wt + 14848;                  // 3,342,336 floats
    unsigned* xtb = (unsigned*)(aff + (size_t)BB * AFFC * HWX);      // 4,456,448 u32 (bf16 xt)
    unsigned* preb = xtb + (size_t)NSLAB * HWX * (CG / 2);           // 4,456,448 u32 (bf16 pre)

    (void)hipMemsetAsync(stat_sum, 0, 2 * CC * sizeof(float), stream);

    wt_kernel<<<dim3(153), dim3(256), 0, stream>>>(dc_w, tm_w, dc_wt, tm_wt);
    transpose_kernel<<<dim3(BB * GG * HH), dim3(256), 0, stream>>>(x, xtb);
    aff_conv_kernel<<<dim3(HWX / 256, GG, BB), dim3(256), 0, stream>>>(xtb, tm_wt, tm_b, aff);
    deform_kernel<<<dim3(NWG), dim3(16, 16), 0, stream>>>(
        xtb, dc_wt, aff, preb, stat_sum, stat_sqs);
    stat_finalize_kernel<<<dim3((CC + 63) / 64), dim3(64), 0, stream>>>(
        stat_sum, stat_sqs, gamma, beta, scale, shift);
    bn_res_relu_kernel<<<dim3(NSLAB * 16), dim3(256), 0, stream>>>(
        preb, x, scale, shift, out);
}